// Round 5
// baseline (447.822 us; speedup 1.0000x reference)
//
#include <hip/hip_runtime.h>
#include <stdint.h>

// Problem constants (reference: T=4096, H=2048, I=768, E=16, TOP_K=2)
#define T_TOK 4096
#define HDIM  2048
#define IDIM  768
#define NEXP  16
#define NPAIR (T_TOK * 2)        // 8192 (token, expert) pairs, exactly top-2
#define PAIR_CAP (NPAIR + 256)   // padded row bound for tile reads past segment end

typedef float f32x4 __attribute__((ext_vector_type(4)));
typedef __bf16 bf16x8 __attribute__((ext_vector_type(8)));
typedef unsigned short u16x8 __attribute__((ext_vector_type(8)));
typedef unsigned int u32;

__device__ __forceinline__ unsigned short f2bf(float f) {
  u32 u = __float_as_uint(f);
  u += 0x7FFFu + ((u >> 16) & 1u);
  return (unsigned short)(u >> 16);
}

__device__ __forceinline__ unsigned short tb(int m) {
  // 2-bit code m in {0,1,2} -> bf16 of {-1, 0, +1}
  return m == 0 ? (unsigned short)0xBF80 : (m == 2 ? (unsigned short)0x3F80 : (unsigned short)0);
}

__device__ __forceinline__ f32x4 mfma16(bf16x8 a, bf16x8 b, f32x4 c) {
  return __builtin_amdgcn_mfma_f32_16x16x32_bf16(a, b, c, 0, 0, 0);
}

// ---------------- routing ----------------
__global__ __launch_bounds__(256) void route_kernel(
    const float* __restrict__ logits, int* __restrict__ counts,
    int* __restrict__ t2i, float* __restrict__ t2w) {
  const int t = blockIdx.x * 256 + threadIdx.x;
  if (t >= T_TOK) return;
  const float* l = logits + t * NEXP;
  float m0 = -1e30f, m1 = -1e30f;
  int i0 = 0, i1 = 0;
#pragma unroll
  for (int j = 0; j < NEXP; ++j) {
    const float v = l[j];
    if (v > m0) { m1 = m0; i1 = i0; m0 = v; i0 = j; }
    else if (v > m1) { m1 = v; i1 = j; }
  }
  const float w0 = 1.0f / (1.0f + expf(m1 - m0));  // renormalized top-2 softmax
  t2i[t] = i0 | (i1 << 8);
  t2w[t] = w0;
  atomicAdd(&counts[i0], 1);
  atomicAdd(&counts[i1], 1);
}

__global__ void scan_kernel(const int* __restrict__ counts,
                            int* __restrict__ offs, int* __restrict__ cursor) {
  if (threadIdx.x == 0) {
    int s = 0;
    for (int e = 0; e < NEXP; ++e) { offs[e] = s; cursor[e] = s; s += counts[e]; }
    offs[NEXP] = s;
  }
}

__global__ __launch_bounds__(256) void fill_kernel(
    const int* __restrict__ t2i, const float* __restrict__ t2w,
    int* __restrict__ cursor, int* __restrict__ pair_token,
    float* __restrict__ pair_wt, int* __restrict__ pair_eid,
    int* __restrict__ t2p0, int* __restrict__ t2p1) {
  const int t = blockIdx.x * 256 + threadIdx.x;
  if (t >= T_TOK) return;
  const int ii = t2i[t];
  const float w0 = t2w[t];
  const int i0 = ii & 255, i1 = (ii >> 8) & 255;
  const int p0 = atomicAdd(&cursor[i0], 1);
  pair_token[p0] = t; pair_wt[p0] = w0; pair_eid[p0] = i0;
  const int p1 = atomicAdd(&cursor[i1], 1);
  pair_token[p1] = t; pair_wt[p1] = 1.0f - w0; pair_eid[p1] = i1;
  t2p0[t] = p0; t2p1[t] = p1;
}

// ---------------- repack: int32-widened packed bytes -> dense u32 ----------------
__global__ __launch_bounds__(256) void repack_kernel(
    const int* __restrict__ w, u32* __restrict__ o) {
  const int j0 = (blockIdx.x * 256 + threadIdx.x) * 4;
  const int4* w4 = (const int4*)w;
  uint4 r;
#pragma unroll
  for (int k = 0; k < 4; ++k) {
    const int4 a = w4[j0 + k];
    ((u32*)&r)[k] = (u32)(a.x & 255) | ((u32)(a.y & 255) << 8) |
                    ((u32)(a.z & 255) << 16) | ((u32)(a.w & 255) << 24);
  }
  ((uint4*)o)[blockIdx.x * 256 + threadIdx.x] = r;
}

// ---------------- xg prepass: xg[p,h] = bf16(x[tok(p),h] * a13[e(p),h]) ----------------
__global__ __launch_bounds__(256) void xg_kernel(
    const float* __restrict__ x, const int* __restrict__ a13q,
    const float* __restrict__ s13p, const int* __restrict__ pair_token,
    const int* __restrict__ pair_eid, unsigned short* __restrict__ xg) {
  const int p = blockIdx.x;
  const int t = pair_token[p];
  const int e = pair_eid[p];
  const float s13 = *s13p;
  const int h0 = threadIdx.x * 8;
  const float* xp = x + (size_t)t * HDIM + h0;
  const int* ap = a13q + (size_t)e * HDIM + h0;
  const float4 x0 = ((const float4*)xp)[0];
  const float4 x1 = ((const float4*)xp)[1];
  const int4 a0 = ((const int4*)ap)[0];
  const int4 a1 = ((const int4*)ap)[1];
  u16x8 q;
  q[0] = f2bf(x0.x * (float)a0.x * s13);
  q[1] = f2bf(x0.y * (float)a0.y * s13);
  q[2] = f2bf(x0.z * (float)a0.z * s13);
  q[3] = f2bf(x0.w * (float)a0.w * s13);
  q[4] = f2bf(x1.x * (float)a1.x * s13);
  q[5] = f2bf(x1.y * (float)a1.y * s13);
  q[6] = f2bf(x1.z * (float)a1.z * s13);
  q[7] = f2bf(x1.w * (float)a1.w * s13);
  *(u16x8*)(xg + (size_t)p * HDIM + h0) = q;
}

// B staging: one u32 (16 codes) -> 16 bf16 into sB[buf], via LDS LUT
#define STAGE_B(buf, wb)                                                   \
  {                                                                        \
    unsigned short* dst = &sB[buf][sBoff];                                 \
    const uint2 q0 = lut[(wb) & 255], q1 = lut[((wb) >> 8) & 255];         \
    const uint2 q2 = lut[((wb) >> 16) & 255], q3 = lut[(wb) >> 24];        \
    *(uint2*)(dst + 0) = q0;                                               \
    *(uint2*)(dst + 4) = q1;                                               \
    *(uint2*)(dst + 8) = q2;                                               \
    *(uint2*)(dst + 12) = q3;                                              \
  }

// A frags direct from global (16 B contiguous per lane per frag)
#define LOAD_A(dst, kt)                                                    \
  {                                                                        \
    dst[0] = *(const bf16x8*)(ap0 + (kt) * 32);                            \
    dst[1] = *(const bf16x8*)(ap1 + (kt) * 32);                            \
    dst[2] = *(const bf16x8*)(ap2 + (kt) * 32);                            \
    dst[3] = *(const bf16x8*)(ap3 + (kt) * 32);                            \
  }

// ---------------- GEMM1: act'[pair,i] = wt * silu(g) * u * a2 ----------------
// Block 128 pairs x (64 gate + 64 up). Waves 2x2, each 64x64. A-frags direct
// from L2 (no sA, no DMA drain). sB double-buffered, ONE barrier per kt:
// stage B(kt+1) + prefetch B word + issue A(kt+1) loads, MFMA(kt), barrier.
__global__ __launch_bounds__(256, 3) void gemm1_kernel(
    const u32* __restrict__ wq13, const int* __restrict__ a2q,
    const float* __restrict__ s2p, const int* __restrict__ counts,
    const int* __restrict__ offs, const float* __restrict__ pair_wt,
    const unsigned short* __restrict__ xg, unsigned short* __restrict__ act) {
  const int id = blockIdx.x;
  const int xcd = id & 7, sblk = id >> 3;
  const int nT = sblk % 12;                 // 0..11 : i-range nT*64..+63
  const int gg = (sblk / 12) * 8 + xcd;     // gg%8 == xcd
  const int e = gg & 15, mT = gg >> 4;      // e%8 == xcd -> per-expert XCD affinity
  const int cnt = counts[e];
  if (mT * 128 >= cnt) return;
  const int base = offs[e];
  const int tid = threadIdx.x;

  __shared__ unsigned short sB[2][128 * 36 + 8];  // pitch 36: conflict-free frag reads
  __shared__ uint2 lut[256];                      // byte -> 4 bf16 ternary values

  {
    const int b = tid;
    const u32 lo = (u32)tb(b & 3) | ((u32)tb((b >> 2) & 3) << 16);
    const u32 hi = (u32)tb((b >> 4) & 3) | ((u32)tb((b >> 6) & 3) << 16);
    lut[b] = make_uint2(lo, hi);
  }
  __syncthreads();

  const int wave = tid >> 6, lane = tid & 63;
  const int wm = wave >> 1, wn = wave & 1;   // 2x2 wave grid
  const int quad = lane >> 4, ln = lane & 15;

  const int bn = tid >> 1, bhalf = tid & 1;
  const int grow = (bn < 64) ? (nT * 64 + bn) : (IDIM + nT * 64 + (bn - 64));
  const u32* browp = wq13 + ((size_t)e * (2 * IDIM) + grow) * (HDIM / 16) + bhalf;
  const int sBoff = bn * 36 + (bhalf << 4);

  const size_t arow0 = (size_t)(base + mT * 128);
  const unsigned short* ap0 = xg + (arow0 + wm * 64 + ln) * HDIM + quad * 8;
  const unsigned short* ap1 = ap0 + 16 * (size_t)HDIM;
  const unsigned short* ap2 = ap0 + 32 * (size_t)HDIM;
  const unsigned short* ap3 = ap0 + 48 * (size_t)HDIM;

  f32x4 acc[4][4] = {};
  bf16x8 afA[4], afB[4];

  // prologue
  u32 wb = browp[0];
  STAGE_B(0, wb);
  u32 wbn = browp[2];
  LOAD_A(afA, 0);
  __syncthreads();

#define G1_MFMA(buf, af)                                                          \
  {                                                                               \
    bf16x8 b0 = *(const bf16x8*)(&sB[buf][(wn * 32 + ln) * 36 + quad * 8]);       \
    bf16x8 b1 = *(const bf16x8*)(&sB[buf][(wn * 32 + 16 + ln) * 36 + quad * 8]);  \
    bf16x8 b2 = *(const bf16x8*)(&sB[buf][(64 + wn * 32 + ln) * 36 + quad * 8]);  \
    bf16x8 b3 = *(const bf16x8*)(&sB[buf][(64 + wn * 32 + 16 + ln) * 36 + quad * 8]); \
    _Pragma("unroll") for (int mi = 0; mi < 4; ++mi) {                            \
      acc[mi][0] = mfma16(af[mi], b0, acc[mi][0]);                                \
      acc[mi][1] = mfma16(af[mi], b1, acc[mi][1]);                                \
      acc[mi][2] = mfma16(af[mi], b2, acc[mi][2]);                                \
      acc[mi][3] = mfma16(af[mi], b3, acc[mi][3]);                                \
    }                                                                             \
  }

  for (int kt = 0; kt < HDIM / 32; kt += 2) {
    {  // even: compute buf0, stage buf1 for kt+1
      STAGE_B(1, wbn);
      wbn = browp[(kt + 2) * 2];  // prefetch word for kt+2 (tail read harmless, in-ws)
      LOAD_A(afB, kt + 1);
      G1_MFMA(0, afA);
      __syncthreads();
    }
    {  // odd: compute buf1, stage buf0 for kt+2
      if (kt + 2 < HDIM / 32) {
        STAGE_B(0, wbn);
        wbn = browp[(kt + 3) * 2];
        LOAD_A(afA, kt + 2);
      }
      G1_MFMA(1, afB);
      __syncthreads();
    }
  }

  // epilogue: act' = bf16(wt * silu(gate) * up * a2[e,i])   (router weight folded in)
  const float s2 = *s2p;
#pragma unroll
  for (int gi = 0; gi < 2; ++gi) {
    const int i = nT * 64 + wn * 32 + gi * 16 + ln;
    const float a2v = (float)a2q[e * IDIM + i] * s2;
#pragma unroll
    for (int mi = 0; mi < 4; ++mi) {
      const f32x4 g = acc[mi][gi];
      const f32x4 u = acc[mi][gi + 2];
#pragma unroll
      for (int r = 0; r < 4; ++r) {
        const int m = mT * 128 + wm * 64 + mi * 16 + quad * 4 + r;
        if (m < cnt) {
          const float wt = pair_wt[base + m];
          const float gv = g[r];
          const float av = gv / (1.0f + __expf(-gv)) * u[r] * a2v * wt;
          act[(size_t)(base + m) * IDIM + i] = f2bf(av);
        }
      }
    }
  }
}

// ---------------- GEMM2: down[pair,h] = act' . tern2  (act pre-weighted, bf16 out) ----------------
__global__ __launch_bounds__(256, 3) void gemm2_kernel(
    const u32* __restrict__ wq2, const int* __restrict__ counts,
    const int* __restrict__ offs, const unsigned short* __restrict__ act,
    unsigned short* __restrict__ down) {
  const int id = blockIdx.x;
  const int xcd = id & 7, sblk = id >> 3;
  const int nT = sblk & 15;                 // 0..15 : h-range nT*128..+127
  const int gg = (sblk >> 4) * 8 + xcd;
  const int e = gg & 15, mT = gg >> 4;
  const int cnt = counts[e];
  if (mT * 128 >= cnt) return;
  const int base = offs[e];
  const int tid = threadIdx.x;

  __shared__ unsigned short sB[2][128 * 36 + 8];
  __shared__ uint2 lut[256];

  {
    const int b = tid;
    const u32 lo = (u32)tb(b & 3) | ((u32)tb((b >> 2) & 3) << 16);
    const u32 hi = (u32)tb((b >> 4) & 3) | ((u32)tb((b >> 6) & 3) << 16);
    lut[b] = make_uint2(lo, hi);
  }
  __syncthreads();

  const int wave = tid >> 6, lane = tid & 63;
  const int wm = wave >> 1, wn = wave & 1;
  const int quad = lane >> 4, ln = lane & 15;

  const int bn = tid >> 1, bhalf = tid & 1;
  const u32* browp = wq2 + ((size_t)e * HDIM + nT * 128 + bn) * (IDIM / 16) + bhalf;
  const int sBoff = bn * 36 + (bhalf << 4);

  const size_t arow0 = (size_t)(base + mT * 128);
  const unsigned short* ap0 = act + (arow0 + wm * 64 + ln) * IDIM + quad * 8;
  const unsigned short* ap1 = ap0 + 16 * (size_t)IDIM;
  const unsigned short* ap2 = ap0 + 32 * (size_t)IDIM;
  const unsigned short* ap3 = ap0 + 48 * (size_t)IDIM;

  f32x4 acc[4][4] = {};
  bf16x8 afA[4], afB[4];

  u32 wb = browp[0];
  STAGE_B(0, wb);
  u32 wbn = browp[2];
  LOAD_A(afA, 0);
  __syncthreads();

#define G2_MFMA(buf, af)                                                          \
  {                                                                               \
    bf16x8 b0 = *(const bf16x8*)(&sB[buf][(wn * 64 + ln) * 36 + quad * 8]);       \
    bf16x8 b1 = *(const bf16x8*)(&sB[buf][(wn * 64 + 16 + ln) * 36 + quad * 8]);  \
    bf16x8 b2 = *(const bf16x8*)(&sB[buf][(wn * 64 + 32 + ln) * 36 + quad * 8]);  \
    bf16x8 b3 = *(const bf16x8*)(&sB[buf][(wn * 64 + 48 + ln) * 36 + quad * 8]);  \
    _Pragma("unroll") for (int mi = 0; mi < 4; ++mi) {                            \
      acc[mi][0] = mfma16(af[mi], b0, acc[mi][0]);                                \
      acc[mi][1] = mfma16(af[mi], b1, acc[mi][1]);                                \
      acc[mi][2] = mfma16(af[mi], b2, acc[mi][2]);                                \
      acc[mi][3] = mfma16(af[mi], b3, acc[mi][3]);                                \
    }                                                                             \
  }

  for (int kt = 0; kt < IDIM / 32; kt += 2) {
    {
      STAGE_B(1, wbn);
      wbn = browp[(kt + 2) * 2];
      LOAD_A(afB, kt + 1);
      G2_MFMA(0, afA);
      __syncthreads();
    }
    {
      if (kt + 2 < IDIM / 32) {
        STAGE_B(0, wbn);
        wbn = browp[(kt + 3) * 2];
        LOAD_A(afA, kt + 2);
      }
      G2_MFMA(1, afB);
      __syncthreads();
    }
  }

  // epilogue: bf16 down (each token's two rows summed later by combine)
#pragma unroll
  for (int mi = 0; mi < 4; ++mi) {
#pragma unroll
    for (int r = 0; r < 4; ++r) {
      const int ml = wm * 64 + mi * 16 + quad * 4 + r;
      const int m = mT * 128 + ml;
      if (m < cnt) {
        unsigned short* drow = down + (size_t)(base + m) * HDIM + nT * 128 + wn * 64;
#pragma unroll
        for (int ni = 0; ni < 4; ++ni)
          drow[ni * 16 + ln] = f2bf(acc[mi][ni][r]);
      }
    }
  }
}

// ---------------- combine: out[t,:] = down[p0,:] + down[p1,:]  (pre-weighted) ----------------
__global__ __launch_bounds__(256) void combine_kernel(
    const int* __restrict__ t2p0, const int* __restrict__ t2p1,
    const unsigned short* __restrict__ down, float* __restrict__ out) {
  const int t = blockIdx.x;
  const int h = threadIdx.x * 8;
  const u16x8 a = *(const u16x8*)(down + (size_t)t2p0[t] * HDIM + h);
  const u16x8 b = *(const u16x8*)(down + (size_t)t2p1[t] * HDIM + h);
  f32x4 o0, o1;
#pragma unroll
  for (int j = 0; j < 4; ++j) {
    o0[j] = __uint_as_float((u32)a[j] << 16) + __uint_as_float((u32)b[j] << 16);
    o1[j] = __uint_as_float((u32)a[j + 4] << 16) + __uint_as_float((u32)b[j + 4] << 16);
  }
  float* o = out + (size_t)t * HDIM + h;
  *(f32x4*)(o) = o0;
  *(f32x4*)(o + 4) = o1;
}

extern "C" void kernel_launch(void* const* d_in, const int* in_sizes, int n_in,
                              void* d_out, int out_size, void* d_ws, size_t ws_size,
                              hipStream_t stream) {
  const float* x      = (const float*)d_in[0];
  const float* logits = (const float*)d_in[1];
  const int*   w13p   = (const int*)d_in[2];   // harness widens uint8 -> int32
  const int*   a13q   = (const int*)d_in[3];
  const float* s13    = (const float*)d_in[4];
  const int*   w2p    = (const int*)d_in[5];
  const int*   a2q    = (const int*)d_in[6];
  const float* s2     = (const float*)d_in[7];
  float* out = (float*)d_out;

  char* ws = (char*)d_ws;
  int*   counts     = (int*)(ws + 0);
  int*   cursor     = (int*)(ws + 64);
  int*   offs       = (int*)(ws + 128);
  int*   t2i        = (int*)(ws + 256);
  float* t2w        = (float*)(ws + 256 + 4 * T_TOK);
  int*   t2p0       = (int*)(ws + 256 + 8 * T_TOK);
  int*   t2p1       = (int*)(ws + 256 + 12 * T_TOK);
  int*   pair_token = (int*)(ws + 256 + 16 * T_TOK);
  float* pair_wt    = (float*)(ws + 256 + 16 * T_TOK + 4 * PAIR_CAP);
  int*   pair_eid   = (int*)(ws + 256 + 16 * T_TOK + 8 * PAIR_CAP);
  const size_t hdr_end = ((size_t)(256 + 16 * T_TOK + 12 * PAIR_CAP) + 255) & ~(size_t)255;

  const size_t n32_13 = (size_t)NEXP * 2 * IDIM * (HDIM / 16);  // 3,145,728 u32
  const size_t n32_2  = (size_t)NEXP * HDIM * (IDIM / 16);      // 1,572,864 u32
  const size_t rp13_b = n32_13 * 4, rp2_b = n32_2 * 4;          // 12.6 + 6.3 MB
  const size_t xg_b   = (size_t)PAIR_CAP * HDIM * 2;            // 34.6 MB
  // total need = hdr + 18.9 + 34.6 + 13.0 ~ 66.8 MB (proven to fit in rounds 3/4);
  // down (bf16, same size as xg) ALIASES xg: gemm2 reads only act, writes down.

  u32* rp13 = (u32*)(ws + hdr_end);
  u32* rp2  = (u32*)(ws + hdr_end + rp13_b);
  unsigned short* xg  = (unsigned short*)(ws + hdr_end + rp13_b + rp2_b);
  unsigned short* act = (unsigned short*)(ws + hdr_end + rp13_b + rp2_b + xg_b);
  unsigned short* down = xg;  // safe reuse (stream-ordered: gemm1 done before gemm2)

  hipMemsetAsync(counts, 0, 256, stream);
  route_kernel<<<T_TOK / 256, 256, 0, stream>>>(logits, counts, t2i, t2w);
  scan_kernel<<<1, 64, 0, stream>>>(counts, offs, cursor);
  fill_kernel<<<T_TOK / 256, 256, 0, stream>>>(t2i, t2w, cursor, pair_token, pair_wt,
                                               pair_eid, t2p0, t2p1);
  repack_kernel<<<(int)(n32_13 / 1024), 256, 0, stream>>>(w13p, rp13);
  repack_kernel<<<(int)(n32_2 / 1024), 256, 0, stream>>>(w2p, rp2);
  xg_kernel<<<NPAIR, 256, 0, stream>>>(x, a13q, s13, pair_token, pair_eid, xg);

  gemm1_kernel<<<6144, 256, 0, stream>>>(rp13, a2q, s2, counts, offs, pair_wt, xg, act);
  gemm2_kernel<<<8192, 256, 0, stream>>>(rp2, counts, offs, act, down);
  combine_kernel<<<T_TOK, 256, 0, stream>>>(t2p0, t2p1, down, out);
}

// Round 6
// 347.428 us; speedup vs baseline: 1.2890x; 1.2890x over previous
//
#include <hip/hip_runtime.h>
#include <stdint.h>

// Problem constants (reference: T=4096, H=2048, I=768, E=16, TOP_K=2)
#define T_TOK 4096
#define HDIM  2048
#define IDIM  768
#define NEXP  16
#define NPAIR (T_TOK * 2)        // 8192 (token, expert) pairs, exactly top-2
#define PAIR_CAP (NPAIR + 256)   // padded row bound for tile reads past segment end

typedef float f32x4 __attribute__((ext_vector_type(4)));
typedef __bf16 bf16x8 __attribute__((ext_vector_type(8)));
typedef unsigned short u16x8 __attribute__((ext_vector_type(8)));
typedef unsigned int u32;
typedef const __attribute__((address_space(1))) u32* as1_u32p;
typedef __attribute__((address_space(3))) u32* as3_u32p;

__device__ __forceinline__ unsigned short f2bf(float f) {
  u32 u = __float_as_uint(f);
  u += 0x7FFFu + ((u >> 16) & 1u);
  return (unsigned short)(u >> 16);
}

__device__ __forceinline__ unsigned short tb(int m) {
  // 2-bit code m in {0,1,2} -> bf16 of {-1, 0, +1}
  return m == 0 ? (unsigned short)0xBF80 : (m == 2 ? (unsigned short)0x3F80 : (unsigned short)0);
}

__device__ __forceinline__ f32x4 mfma16(bf16x8 a, bf16x8 b, f32x4 c) {
  return __builtin_amdgcn_mfma_f32_16x16x32_bf16(a, b, c, 0, 0, 0);
}

// ---------------- routing ----------------
__global__ __launch_bounds__(256) void route_kernel(
    const float* __restrict__ logits, int* __restrict__ counts,
    int* __restrict__ t2i, float* __restrict__ t2w) {
  const int t = blockIdx.x * 256 + threadIdx.x;
  if (t >= T_TOK) return;
  const float* l = logits + t * NEXP;
  float m0 = -1e30f, m1 = -1e30f;
  int i0 = 0, i1 = 0;
#pragma unroll
  for (int j = 0; j < NEXP; ++j) {
    const float v = l[j];
    if (v > m0) { m1 = m0; i1 = i0; m0 = v; i0 = j; }
    else if (v > m1) { m1 = v; i1 = j; }
  }
  const float w0 = 1.0f / (1.0f + expf(m1 - m0));  // renormalized top-2 softmax
  t2i[t] = i0 | (i1 << 8);
  t2w[t] = w0;
  atomicAdd(&counts[i0], 1);
  atomicAdd(&counts[i1], 1);
}

__global__ void scan_kernel(const int* __restrict__ counts,
                            int* __restrict__ offs, int* __restrict__ cursor) {
  if (threadIdx.x == 0) {
    int s = 0;
    for (int e = 0; e < NEXP; ++e) { offs[e] = s; cursor[e] = s; s += counts[e]; }
    offs[NEXP] = s;
  }
}

__global__ __launch_bounds__(256) void fill_kernel(
    const int* __restrict__ t2i, const float* __restrict__ t2w,
    int* __restrict__ cursor, int* __restrict__ pair_token,
    float* __restrict__ pair_wt, int* __restrict__ pair_eid,
    int* __restrict__ t2p0, int* __restrict__ t2p1) {
  const int t = blockIdx.x * 256 + threadIdx.x;
  if (t >= T_TOK) return;
  const int ii = t2i[t];
  const float w0 = t2w[t];
  const int i0 = ii & 255, i1 = (ii >> 8) & 255;
  const int p0 = atomicAdd(&cursor[i0], 1);
  pair_token[p0] = t; pair_wt[p0] = w0; pair_eid[p0] = i0;
  const int p1 = atomicAdd(&cursor[i1], 1);
  pair_token[p1] = t; pair_wt[p1] = 1.0f - w0; pair_eid[p1] = i1;
  t2p0[t] = p0; t2p1[t] = p1;
}

// ---------------- repack: int32-widened packed bytes -> dense u32 ----------------
__global__ __launch_bounds__(256) void repack_kernel(
    const int* __restrict__ w, u32* __restrict__ o) {
  const int j0 = (blockIdx.x * 256 + threadIdx.x) * 4;
  const int4* w4 = (const int4*)w;
  uint4 r;
#pragma unroll
  for (int k = 0; k < 4; ++k) {
    const int4 a = w4[j0 + k];
    ((u32*)&r)[k] = (u32)(a.x & 255) | ((u32)(a.y & 255) << 8) |
                    ((u32)(a.z & 255) << 16) | ((u32)(a.w & 255) << 24);
  }
  ((uint4*)o)[blockIdx.x * 256 + threadIdx.x] = r;
}

// ---------------- xg prepass: xg[p,h] = bf16(x[tok(p),h] * a13[e(p),h]) ----------------
__global__ __launch_bounds__(256) void xg_kernel(
    const float* __restrict__ x, const int* __restrict__ a13q,
    const float* __restrict__ s13p, const int* __restrict__ pair_token,
    const int* __restrict__ pair_eid, unsigned short* __restrict__ xg) {
  const int p = blockIdx.x;
  const int t = pair_token[p];
  const int e = pair_eid[p];
  const float s13 = *s13p;
  const int h0 = threadIdx.x * 8;
  const float* xp = x + (size_t)t * HDIM + h0;
  const int* ap = a13q + (size_t)e * HDIM + h0;
  const float4 x0 = ((const float4*)xp)[0];
  const float4 x1 = ((const float4*)xp)[1];
  const int4 a0 = ((const int4*)ap)[0];
  const int4 a1 = ((const int4*)ap)[1];
  u16x8 q;
  q[0] = f2bf(x0.x * (float)a0.x * s13);
  q[1] = f2bf(x0.y * (float)a0.y * s13);
  q[2] = f2bf(x0.z * (float)a0.z * s13);
  q[3] = f2bf(x0.w * (float)a0.w * s13);
  q[4] = f2bf(x1.x * (float)a1.x * s13);
  q[5] = f2bf(x1.y * (float)a1.y * s13);
  q[6] = f2bf(x1.z * (float)a1.z * s13);
  q[7] = f2bf(x1.w * (float)a1.w * s13);
  *(u16x8*)(xg + (size_t)p * HDIM + h0) = q;
}

// stage one u32 (16 codes -> 16 bf16) into sBx at sBoff via LDS LUT
#define STAGE_B(sBx, wb)                                                   \
  {                                                                        \
    unsigned short* dst = sBx + sBoff;                                     \
    const uint2 q0 = lut[(wb) & 255], q1 = lut[((wb) >> 8) & 255];         \
    const uint2 q2 = lut[((wb) >> 16) & 255], q3 = lut[(wb) >> 24];        \
    *(uint2*)(dst + 0) = q0;                                               \
    *(uint2*)(dst + 4) = q1;                                               \
    *(uint2*)(dst + 8) = q2;                                               \
    *(uint2*)(dst + 12) = q3;                                              \
  }

// ---------------- GEMM1: act'[pair,i] = wt * silu(g) * u * a2 ----------------
// Block 128 pairs x (64 gate + 64 up). Waves 2x2 (64x64). BK=64 per stage:
// DMA sA0/sA1 (two 128x32 halves) + stage sB0/sB1 from one aligned uint4 of
// codes, ONE barrier, 2x MFMA batches, barrier. Halves barrier count vs BK=32.
__global__ __launch_bounds__(256, 4) void gemm1_kernel(
    const u32* __restrict__ wq13, const int* __restrict__ a2q,
    const float* __restrict__ s2p, const int* __restrict__ counts,
    const int* __restrict__ offs, const float* __restrict__ pair_wt,
    const unsigned short* __restrict__ xg, unsigned short* __restrict__ act) {
  const int id = blockIdx.x;
  const int xcd = id & 7, sblk = id >> 3;
  const int nT = sblk % 12;                 // 0..11 : i-range nT*64..+63
  const int gg = (sblk / 12) * 8 + xcd;     // gg%8 == xcd
  const int e = gg & 15, mT = gg >> 4;      // e%8 == xcd -> per-expert XCD affinity
  const int cnt = counts[e];
  if (mT * 128 >= cnt) return;
  const int base = offs[e];
  const int tid = threadIdx.x;

  __shared__ unsigned short sA0[128 * 32];      // k-lo half (DMA layout, unpadded)
  __shared__ unsigned short sA1[128 * 32];      // k-hi half
  __shared__ unsigned short sB0[128 * 36 + 8];  // pitch 36: conflict-free frag reads
  __shared__ unsigned short sB1[128 * 36 + 8];
  __shared__ uint2 lut[256];                    // byte -> 4 bf16 ternary values

  {
    const int b = tid;
    const u32 lo = (u32)tb(b & 3) | ((u32)tb((b >> 2) & 3) << 16);
    const u32 hi = (u32)tb((b >> 4) & 3) | ((u32)tb((b >> 6) & 3) << 16);
    lut[b] = make_uint2(lo, hi);
  }
  __syncthreads();

  const int wave = tid >> 6, lane = tid & 63;
  const int wm = wave >> 1, wn = wave & 1;   // 2x2 wave grid
  const int quad = lane >> 4, ln = lane & 15;

  // B: 2 threads/row; per stage each thread loads one aligned uint4 = 64 codes span
  const int bn = tid >> 1, bhalf = tid & 1;
  const int grow = (bn < 64) ? (nT * 64 + bn) : (IDIM + nT * 64 + (bn - 64));
  const u32* browp = wq13 + ((size_t)e * (2 * IDIM) + grow) * (HDIM / 16);
  const int sBoff = bn * 36 + (bhalf << 4);

  // A DMA: 16 rows x 32 cols per instr; 4 instrs/wave/stage (2 per half)
  const int arow = lane >> 2;
  const int acol = (lane & 3) * 8;
  const size_t arow0 = (size_t)(base + mT * 128);

  f32x4 acc[4][4] = {};

#define G1_MFMA(sAx, sBx)                                                          \
  {                                                                                \
    bf16x8 af[4];                                                                  \
    _Pragma("unroll") for (int mi = 0; mi < 4; ++mi)                               \
        af[mi] = *(const bf16x8*)(sAx + (wm * 64 + mi * 16 + ln) * 32 + quad * 8); \
    bf16x8 b0 = *(const bf16x8*)(sBx + (wn * 32 + ln) * 36 + quad * 8);            \
    bf16x8 b1 = *(const bf16x8*)(sBx + (wn * 32 + 16 + ln) * 36 + quad * 8);       \
    bf16x8 b2 = *(const bf16x8*)(sBx + (64 + wn * 32 + ln) * 36 + quad * 8);       \
    bf16x8 b3 = *(const bf16x8*)(sBx + (64 + wn * 32 + 16 + ln) * 36 + quad * 8);  \
    _Pragma("unroll") for (int mi = 0; mi < 4; ++mi) {                             \
      acc[mi][0] = mfma16(af[mi], b0, acc[mi][0]);                                 \
      acc[mi][1] = mfma16(af[mi], b1, acc[mi][1]);                                 \
      acc[mi][2] = mfma16(af[mi], b2, acc[mi][2]);                                 \
      acc[mi][3] = mfma16(af[mi], b3, acc[mi][3]);                                 \
    }                                                                              \
  }

  for (int s = 0; s < HDIM / 64; ++s) {
    const uint4 W = *(const uint4*)(browp + 4 * s);  // 16B aligned (row*128 u32s)
#pragma unroll
    for (int c = 0; c < 2; ++c) {
      const unsigned short* gp =
          xg + (arow0 + wave * 32 + c * 16 + arow) * HDIM + s * 64 + acol;
      unsigned short* lp = sA0 + (wave * 32 + c * 16) * 32;  // wave-uniform base
      __builtin_amdgcn_global_load_lds((as1_u32p)(const void*)gp, (as3_u32p)(void*)lp, 16, 0, 0);
    }
#pragma unroll
    for (int c = 0; c < 2; ++c) {
      const unsigned short* gp =
          xg + (arow0 + wave * 32 + c * 16 + arow) * HDIM + s * 64 + 32 + acol;
      unsigned short* lp = sA1 + (wave * 32 + c * 16) * 32;
      __builtin_amdgcn_global_load_lds((as1_u32p)(const void*)gp, (as3_u32p)(void*)lp, 16, 0, 0);
    }
    {
      const u32 wlo = bhalf ? W.y : W.x;  // k 64s+16*bhalf .. +15
      const u32 whi = bhalf ? W.w : W.z;  // k 64s+32+16*bhalf .. +15
      STAGE_B(sB0, wlo);
      STAGE_B(sB1, whi);
    }
    __syncthreads();
    G1_MFMA(sA0, sB0);
    G1_MFMA(sA1, sB1);
    __syncthreads();
  }

  // epilogue: act' = bf16(wt * silu(gate) * up * a2[e,i])   (router weight folded in)
  const float s2 = *s2p;
#pragma unroll
  for (int gi = 0; gi < 2; ++gi) {
    const int i = nT * 64 + wn * 32 + gi * 16 + ln;
    const float a2v = (float)a2q[e * IDIM + i] * s2;
#pragma unroll
    for (int mi = 0; mi < 4; ++mi) {
      const f32x4 g = acc[mi][gi];
      const f32x4 u = acc[mi][gi + 2];
#pragma unroll
      for (int r = 0; r < 4; ++r) {
        const int m = mT * 128 + wm * 64 + mi * 16 + quad * 4 + r;
        if (m < cnt) {
          const float wt = pair_wt[base + m];
          const float gv = g[r];
          const float av = gv / (1.0f + __expf(-gv)) * u[r] * a2v * wt;
          act[(size_t)(base + m) * IDIM + i] = f2bf(av);
        }
      }
    }
  }
}

// ---------------- GEMM2: down[pair,h] = act' . tern2  (act pre-weighted, bf16 out) ----------------
__global__ __launch_bounds__(256, 4) void gemm2_kernel(
    const u32* __restrict__ wq2, const int* __restrict__ counts,
    const int* __restrict__ offs, const unsigned short* __restrict__ act,
    unsigned short* __restrict__ down) {
  const int id = blockIdx.x;
  const int xcd = id & 7, sblk = id >> 3;
  const int nT = sblk & 15;                 // 0..15 : h-range nT*128..+127
  const int gg = (sblk >> 4) * 8 + xcd;
  const int e = gg & 15, mT = gg >> 4;
  const int cnt = counts[e];
  if (mT * 128 >= cnt) return;
  const int base = offs[e];
  const int tid = threadIdx.x;

  __shared__ unsigned short sA0[128 * 32];
  __shared__ unsigned short sA1[128 * 32];
  __shared__ unsigned short sB0[128 * 36 + 8];
  __shared__ unsigned short sB1[128 * 36 + 8];
  __shared__ uint2 lut[256];

  {
    const int b = tid;
    const u32 lo = (u32)tb(b & 3) | ((u32)tb((b >> 2) & 3) << 16);
    const u32 hi = (u32)tb((b >> 4) & 3) | ((u32)tb((b >> 6) & 3) << 16);
    lut[b] = make_uint2(lo, hi);
  }
  __syncthreads();

  const int wave = tid >> 6, lane = tid & 63;
  const int wm = wave >> 1, wn = wave & 1;
  const int quad = lane >> 4, ln = lane & 15;

  const int bn = tid >> 1, bhalf = tid & 1;
  const u32* browp = wq2 + ((size_t)e * HDIM + nT * 128 + bn) * (IDIM / 16);
  const int sBoff = bn * 36 + (bhalf << 4);

  const int arow = lane >> 2;
  const int acol = (lane & 3) * 8;
  const size_t arow0 = (size_t)(base + mT * 128);

  f32x4 acc[4][4] = {};

#define G2_MFMA(sAx, sBx)                                                          \
  {                                                                                \
    bf16x8 af[4];                                                                  \
    _Pragma("unroll") for (int mi = 0; mi < 4; ++mi)                               \
        af[mi] = *(const bf16x8*)(sAx + (wm * 64 + mi * 16 + ln) * 32 + quad * 8); \
    bf16x8 b0 = *(const bf16x8*)(sBx + (wn * 64 + ln) * 36 + quad * 8);            \
    bf16x8 b1 = *(const bf16x8*)(sBx + (wn * 64 + 16 + ln) * 36 + quad * 8);       \
    bf16x8 b2 = *(const bf16x8*)(sBx + (wn * 64 + 32 + ln) * 36 + quad * 8);       \
    bf16x8 b3 = *(const bf16x8*)(sBx + (wn * 64 + 48 + ln) * 36 + quad * 8);       \
    _Pragma("unroll") for (int mi = 0; mi < 4; ++mi) {                             \
      acc[mi][0] = mfma16(af[mi], b0, acc[mi][0]);                                 \
      acc[mi][1] = mfma16(af[mi], b1, acc[mi][1]);                                 \
      acc[mi][2] = mfma16(af[mi], b2, acc[mi][2]);                                 \
      acc[mi][3] = mfma16(af[mi], b3, acc[mi][3]);                                 \
    }                                                                              \
  }

  for (int s = 0; s < IDIM / 64; ++s) {
    const uint4 W = *(const uint4*)(browp + 4 * s);  // 16B aligned (row*48 u32s)
#pragma unroll
    for (int c = 0; c < 2; ++c) {
      const unsigned short* gp =
          act + (arow0 + wave * 32 + c * 16 + arow) * IDIM + s * 64 + acol;
      unsigned short* lp = sA0 + (wave * 32 + c * 16) * 32;
      __builtin_amdgcn_global_load_lds((as1_u32p)(const void*)gp, (as3_u32p)(void*)lp, 16, 0, 0);
    }
#pragma unroll
    for (int c = 0; c < 2; ++c) {
      const unsigned short* gp =
          act + (arow0 + wave * 32 + c * 16 + arow) * IDIM + s * 64 + 32 + acol;
      unsigned short* lp = sA1 + (wave * 32 + c * 16) * 32;
      __builtin_amdgcn_global_load_lds((as1_u32p)(const void*)gp, (as3_u32p)(void*)lp, 16, 0, 0);
    }
    {
      const u32 wlo = bhalf ? W.y : W.x;
      const u32 whi = bhalf ? W.w : W.z;
      STAGE_B(sB0, wlo);
      STAGE_B(sB1, whi);
    }
    __syncthreads();
    G2_MFMA(sA0, sB0);
    G2_MFMA(sA1, sB1);
    __syncthreads();
  }

  // epilogue: bf16 down (each token's two rows summed later by combine)
#pragma unroll
  for (int mi = 0; mi < 4; ++mi) {
#pragma unroll
    for (int r = 0; r < 4; ++r) {
      const int ml = wm * 64 + mi * 16 + quad * 4 + r;
      const int m = mT * 128 + ml;
      if (m < cnt) {
        unsigned short* drow = down + (size_t)(base + m) * HDIM + nT * 128 + wn * 64;
#pragma unroll
        for (int ni = 0; ni < 4; ++ni)
          drow[ni * 16 + ln] = f2bf(acc[mi][ni][r]);
      }
    }
  }
}

// ---------------- combine: out[t,:] = down[p0,:] + down[p1,:]  (pre-weighted) ----------------
__global__ __launch_bounds__(256) void combine_kernel(
    const int* __restrict__ t2p0, const int* __restrict__ t2p1,
    const unsigned short* __restrict__ down, float* __restrict__ out) {
  const int t = blockIdx.x;
  const int h = threadIdx.x * 8;
  const u16x8 a = *(const u16x8*)(down + (size_t)t2p0[t] * HDIM + h);
  const u16x8 b = *(const u16x8*)(down + (size_t)t2p1[t] * HDIM + h);
  f32x4 o0, o1;
#pragma unroll
  for (int j = 0; j < 4; ++j) {
    o0[j] = __uint_as_float((u32)a[j] << 16) + __uint_as_float((u32)b[j] << 16);
    o1[j] = __uint_as_float((u32)a[j + 4] << 16) + __uint_as_float((u32)b[j + 4] << 16);
  }
  float* o = out + (size_t)t * HDIM + h;
  *(f32x4*)(o) = o0;
  *(f32x4*)(o + 4) = o1;
}

extern "C" void kernel_launch(void* const* d_in, const int* in_sizes, int n_in,
                              void* d_out, int out_size, void* d_ws, size_t ws_size,
                              hipStream_t stream) {
  const float* x      = (const float*)d_in[0];
  const float* logits = (const float*)d_in[1];
  const int*   w13p   = (const int*)d_in[2];   // harness widens uint8 -> int32
  const int*   a13q   = (const int*)d_in[3];
  const float* s13    = (const float*)d_in[4];
  const int*   w2p    = (const int*)d_in[5];
  const int*   a2q    = (const int*)d_in[6];
  const float* s2     = (const float*)d_in[7];
  float* out = (float*)d_out;

  char* ws = (char*)d_ws;
  int*   counts     = (int*)(ws + 0);
  int*   cursor     = (int*)(ws + 64);
  int*   offs       = (int*)(ws + 128);
  int*   t2i        = (int*)(ws + 256);
  float* t2w        = (float*)(ws + 256 + 4 * T_TOK);
  int*   t2p0       = (int*)(ws + 256 + 8 * T_TOK);
  int*   t2p1       = (int*)(ws + 256 + 12 * T_TOK);
  int*   pair_token = (int*)(ws + 256 + 16 * T_TOK);
  float* pair_wt    = (float*)(ws + 256 + 16 * T_TOK + 4 * PAIR_CAP);
  int*   pair_eid   = (int*)(ws + 256 + 16 * T_TOK + 8 * PAIR_CAP);
  const size_t hdr_end = ((size_t)(256 + 16 * T_TOK + 12 * PAIR_CAP) + 255) & ~(size_t)255;

  const size_t n32_13 = (size_t)NEXP * 2 * IDIM * (HDIM / 16);  // 3,145,728 u32
  const size_t n32_2  = (size_t)NEXP * HDIM * (IDIM / 16);      // 1,572,864 u32
  const size_t rp13_b = n32_13 * 4, rp2_b = n32_2 * 4;          // 12.6 + 6.3 MB
  const size_t xg_b   = (size_t)PAIR_CAP * HDIM * 2;            // 34.6 MB
  // total need = hdr + 18.9 + 34.6 + 13.0 ~ 66.8 MB (proven to fit);
  // down (bf16, same size as xg) ALIASES xg: gemm2 reads only act, writes down.

  u32* rp13 = (u32*)(ws + hdr_end);
  u32* rp2  = (u32*)(ws + hdr_end + rp13_b);
  unsigned short* xg  = (unsigned short*)(ws + hdr_end + rp13_b + rp2_b);
  unsigned short* act = (unsigned short*)(ws + hdr_end + rp13_b + rp2_b + xg_b);
  unsigned short* down = xg;  // safe reuse (stream-ordered: gemm1 done before gemm2)

  hipMemsetAsync(counts, 0, 256, stream);
  route_kernel<<<T_TOK / 256, 256, 0, stream>>>(logits, counts, t2i, t2w);
  scan_kernel<<<1, 64, 0, stream>>>(counts, offs, cursor);
  fill_kernel<<<T_TOK / 256, 256, 0, stream>>>(t2i, t2w, cursor, pair_token, pair_wt,
                                               pair_eid, t2p0, t2p1);
  repack_kernel<<<(int)(n32_13 / 1024), 256, 0, stream>>>(w13p, rp13);
  repack_kernel<<<(int)(n32_2 / 1024), 256, 0, stream>>>(w2p, rp2);
  xg_kernel<<<NPAIR, 256, 0, stream>>>(x, a13q, s13, pair_token, pair_eid, xg);

  gemm1_kernel<<<6144, 256, 0, stream>>>(rp13, a2q, s2, counts, offs, pair_wt, xg, act);
  gemm2_kernel<<<8192, 256, 0, stream>>>(rp2, counts, offs, act, down);
  combine_kernel<<<T_TOK, 256, 0, stream>>>(t2p0, t2p1, down, out);
}